// Round 8
// baseline (706.736 us; speedup 1.0000x reference)
//
#include <hip/hip_runtime.h>
#include <hip/hip_fp16.h>

#define N_NODES 50000
#define N_EDGES 800000
#define CH 96
#define NSLICE 8          // channel slices; slice = blockIdx % 8 ~ XCD id
#define SCH 12            // channels per slice
#define ROWB 32           // bytes per sliced fp16 row (24B used + 8B pad for alignment)
#define STEPS 10
#define SENT N_NODES      // sentinel src row (kept all-zero in every slice)

// sliced p buffer geometry
#define SLICE_STRIDE 1600256ull                    // align256((N_NODES+1)*ROWB)
#define SLAB        (8ull * SLICE_STRIDE)          // one p_k (all slices), ~12.8 MB

// ---------- CSR build ----------

__global__ void count_deg(const int* __restrict__ ei, int* __restrict__ deg, int ne) {
    int t = blockIdx.x * blockDim.x + threadIdx.x;
    int e = t * 4;
    if (e < ne) {
        int4 d4 = *(const int4*)(ei + ne + e);
        if ((unsigned)d4.x < (unsigned)N_NODES) atomicAdd(&deg[d4.x], 1);
        if ((unsigned)d4.y < (unsigned)N_NODES) atomicAdd(&deg[d4.y], 1);
        if ((unsigned)d4.z < (unsigned)N_NODES) atomicAdd(&deg[d4.z], 1);
        if ((unsigned)d4.w < (unsigned)N_NODES) atomicAdd(&deg[d4.w], 1);
    }
}

// scan1 also computes dinv; row_ptr built over PADDED degrees (round up to 4)
__global__ void scan1(const int* __restrict__ deg, int* __restrict__ row_ptr,
                      int* __restrict__ partials, float* __restrict__ dinv, int n) {
    __shared__ int sm[256];
    int i = blockIdx.x * 256 + threadIdx.x;
    int v = 0;
    if (i < n) {
        int d = deg[i];
        dinv[i] = (d > 0) ? (1.0f / sqrtf((float)d)) : 0.0f;
        v = (d + 3) & ~3;
    }
    sm[threadIdx.x] = v;
    __syncthreads();
    for (int off = 1; off < 256; off <<= 1) {
        int t = (threadIdx.x >= off) ? sm[threadIdx.x - off] : 0;
        __syncthreads();
        sm[threadIdx.x] += t;
        __syncthreads();
    }
    if (i < n) row_ptr[i + 1] = sm[threadIdx.x];
    if (threadIdx.x == 255) partials[blockIdx.x] = sm[255];
}

__global__ void scan2(int* __restrict__ partials, int nb) {
    __shared__ int sm[256];
    int v = (threadIdx.x < nb) ? partials[threadIdx.x] : 0;
    sm[threadIdx.x] = v;
    __syncthreads();
    for (int off = 1; off < 256; off <<= 1) {
        int t = (threadIdx.x >= off) ? sm[threadIdx.x - off] : 0;
        __syncthreads();
        sm[threadIdx.x] += t;
        __syncthreads();
    }
    if (threadIdx.x < nb) partials[threadIdx.x] = sm[threadIdx.x] - v;
}

__global__ void scan3(int* __restrict__ row_ptr, const int* __restrict__ partials, int n) {
    int i = blockIdx.x * 256 + threadIdx.x;
    if (i < n) row_ptr[i + 1] += partials[blockIdx.x];
    if (i == 0) row_ptr[0] = 0;
}

__global__ void pad_fill(const int* __restrict__ deg, const int* __restrict__ row_ptr,
                         unsigned short* __restrict__ cs, int n) {
    int i = blockIdx.x * blockDim.x + threadIdx.x;
    if (i < n) {
        int dg = deg[i];
        int dp = (dg + 3) & ~3;
        int base = row_ptr[i];
        for (int j = dg; j < dp; ++j) cs[base + j] = (unsigned short)SENT;
    }
}

// scatter src (as u16) into dst-grouped slots; deg doubles as cursor via atomicSub
__global__ void fill_csr(const int* __restrict__ ei, const int* __restrict__ row_ptr,
                         int* __restrict__ deg, unsigned short* __restrict__ cs, int ne) {
    int t = blockIdx.x * blockDim.x + threadIdx.x;
    int e = t * 4;
    if (e < ne) {
        int4 s4 = *(const int4*)(ei + e);
        int4 d4 = *(const int4*)(ei + ne + e);
        #pragma unroll
        for (int j = 0; j < 4; ++j) {
            int s = (j == 0) ? s4.x : (j == 1) ? s4.y : (j == 2) ? s4.z : s4.w;
            int d = (j == 0) ? d4.x : (j == 1) ? d4.y : (j == 2) ? d4.z : d4.w;
            if ((unsigned)d >= (unsigned)N_NODES) continue;
            if ((unsigned)s >= (unsigned)N_NODES) s = SENT;
            int slot = atomicSub(&deg[d], 1) - 1;
            cs[row_ptr[d] + slot] = (unsigned short)s;
        }
    }
}

// p0[slice][node] = fp16(dinv[node] * x[node][slice*12 .. +12])
__global__ __launch_bounds__(256) void prescale16(const float* __restrict__ x,
                                                  const float* __restrict__ dinv,
                                                  char* __restrict__ p0) {
    int slice = blockIdx.x & 7;
    int node  = (blockIdx.x >> 3) * 256 + threadIdx.x;
    if (node >= N_NODES) return;
    float dv = dinv[node];
    const float4* xb = (const float4*)((const char*)x + (size_t)node * 384 + slice * 48);
    float4 x0 = xb[0], x1 = xb[1], x2 = xb[2];
    uint4 qa; uint2 qb;
    ((__half2*)&qa)[0] = __floats2half2_rn(dv * x0.x, dv * x0.y);
    ((__half2*)&qa)[1] = __floats2half2_rn(dv * x0.z, dv * x0.w);
    ((__half2*)&qa)[2] = __floats2half2_rn(dv * x1.x, dv * x1.y);
    ((__half2*)&qa)[3] = __floats2half2_rn(dv * x1.z, dv * x1.w);
    ((__half2*)&qb)[0] = __floats2half2_rn(dv * x2.x, dv * x2.y);
    ((__half2*)&qb)[1] = __floats2half2_rn(dv * x2.z, dv * x2.w);
    char* po = p0 + (size_t)slice * SLICE_STRIDE + (size_t)node * ROWB;
    *(uint4*)po = qa;
    *(uint2*)(po + 16) = qb;
}

// zero the sentinel row in every slice of every slab
__global__ void zero_sent(char* __restrict__ p_base, int nbuf) {
    int t = blockIdx.x * blockDim.x + threadIdx.x;
    if (t < nbuf * NSLICE) {
        char* p = p_base + (size_t)(t / NSLICE) * SLAB
                         + (size_t)(t % NSLICE) * SLICE_STRIDE + (size_t)SENT * ROWB;
        uint4 z = {0u, 0u, 0u, 0u};
        *(uint4*)p = z;
        *(uint2*)(p + 16) = make_uint2(0u, 0u);
    }
}

__device__ inline void acc8(float* a, uint4 q) {
    const __half2* h = (const __half2*)&q;
    #pragma unroll
    for (int i = 0; i < 4; ++i) {
        float2 f = __half22float2(h[i]);
        a[2 * i] += f.x; a[2 * i + 1] += f.y;
    }
}
__device__ inline void acc4(float* a, uint2 q) {
    const __half2* h = (const __half2*)&q;
    #pragma unroll
    for (int i = 0; i < 2; ++i) {
        float2 f = __half22float2(h[i]);
        a[2 * i] += f.x; a[2 * i + 1] += f.y;
    }
}

// ---------- propagation (channel-sliced, fp16 storage, fp32 accumulate) ----------
// slice = blockIdx%8 (~XCD): gathers stay inside one 1.6MB L2-resident slice.
// One thread per (node, slice): 12 channels. Deferred mode: out==nullptr.
__global__ __launch_bounds__(256) void prop16(const char* __restrict__ pin_slab,
                                              char* __restrict__ pout_slab,
                                              float* __restrict__ out,
                                              const float* __restrict__ x,
                                              const int* __restrict__ row_ptr,
                                              const unsigned short* __restrict__ cs,
                                              const float* __restrict__ dinv,
                                              const float* __restrict__ gamma, int k) {
    int slice = blockIdx.x & 7;
    int node  = (blockIdx.x >> 3) * 256 + threadIdx.x;
    if (node >= N_NODES) return;
    const char* pin = pin_slab + (size_t)slice * SLICE_STRIDE;
    int beg = row_ptr[node];
    int end = row_ptr[node + 1];          // multiple of 4

    float acc[12];
    #pragma unroll
    for (int i = 0; i < 12; ++i) acc[i] = 0.f;

    for (int e = beg; e < end; e += 4) {
        ushort4 m = *(const ushort4*)(cs + e);
        const char* r0 = pin + (size_t)m.x * ROWB;
        const char* r1 = pin + (size_t)m.y * ROWB;
        const char* r2 = pin + (size_t)m.z * ROWB;
        const char* r3 = pin + (size_t)m.w * ROWB;
        uint4 a0 = *(const uint4*)r0; uint2 b0 = *(const uint2*)(r0 + 16);
        uint4 a1 = *(const uint4*)r1; uint2 b1 = *(const uint2*)(r1 + 16);
        uint4 a2 = *(const uint4*)r2; uint2 b2 = *(const uint2*)(r2 + 16);
        uint4 a3 = *(const uint4*)r3; uint2 b3 = *(const uint2*)(r3 + 16);
        acc8(acc, a0); acc4(acc + 8, b0);
        acc8(acc, a1); acc4(acc + 8, b1);
        acc8(acc, a2); acc4(acc + 8, b2);
        acc8(acc, a3); acc4(acc + 8, b3);
    }

    float dv = dinv[node];

    if (pout_slab) {                       // p_out = fp16(dinv^2 * S)
        float s = dv * dv;
        uint4 qa; uint2 qb;
        ((__half2*)&qa)[0] = __floats2half2_rn(s * acc[0], s * acc[1]);
        ((__half2*)&qa)[1] = __floats2half2_rn(s * acc[2], s * acc[3]);
        ((__half2*)&qa)[2] = __floats2half2_rn(s * acc[4], s * acc[5]);
        ((__half2*)&qa)[3] = __floats2half2_rn(s * acc[6], s * acc[7]);
        ((__half2*)&qb)[0] = __floats2half2_rn(s * acc[8], s * acc[9]);
        ((__half2*)&qb)[1] = __floats2half2_rn(s * acc[10], s * acc[11]);
        char* po = pout_slab + (size_t)slice * SLICE_STRIDE + (size_t)node * ROWB;
        *(uint4*)po = qa;
        *(uint2*)(po + 16) = qb;
    }

    if (out) {                             // fallback: per-step out RMW
        float gk = gamma[k + 1] * dv;      // out += gamma * (dinv*S)
        float4* ob = (float4*)((char*)out + (size_t)node * 384 + slice * 48);
        float4 o0, o1, o2;
        if (k == 0) {
            float g0 = gamma[0];
            const float4* xb = (const float4*)((const char*)x + (size_t)node * 384 + slice * 48);
            float4 x0 = xb[0], x1 = xb[1], x2 = xb[2];
            o0.x = fmaf(gk, acc[0], g0 * x0.x); o0.y = fmaf(gk, acc[1], g0 * x0.y);
            o0.z = fmaf(gk, acc[2], g0 * x0.z); o0.w = fmaf(gk, acc[3], g0 * x0.w);
            o1.x = fmaf(gk, acc[4], g0 * x1.x); o1.y = fmaf(gk, acc[5], g0 * x1.y);
            o1.z = fmaf(gk, acc[6], g0 * x1.z); o1.w = fmaf(gk, acc[7], g0 * x1.w);
            o2.x = fmaf(gk, acc[8], g0 * x2.x); o2.y = fmaf(gk, acc[9], g0 * x2.y);
            o2.z = fmaf(gk, acc[10], g0 * x2.z); o2.w = fmaf(gk, acc[11], g0 * x2.w);
        } else {
            o0 = ob[0]; o1 = ob[1]; o2 = ob[2];
            o0.x = fmaf(gk, acc[0], o0.x); o0.y = fmaf(gk, acc[1], o0.y);
            o0.z = fmaf(gk, acc[2], o0.z); o0.w = fmaf(gk, acc[3], o0.w);
            o1.x = fmaf(gk, acc[4], o1.x); o1.y = fmaf(gk, acc[5], o1.y);
            o1.z = fmaf(gk, acc[6], o1.z); o1.w = fmaf(gk, acc[7], o1.w);
            o2.x = fmaf(gk, acc[8], o2.x); o2.y = fmaf(gk, acc[9], o2.y);
            o2.z = fmaf(gk, acc[10], o2.z); o2.w = fmaf(gk, acc[11], o2.w);
        }
        ob[0] = o0; ob[1] = o1; ob[2] = o2;
    }
}

// deferred: out = gamma0*x + sum_k gamma_k * (p_k / dinv)
__global__ __launch_bounds__(256) void finalize(const char* __restrict__ p_base,
                                                const float* __restrict__ x,
                                                const float* __restrict__ dinv,
                                                const float* __restrict__ gamma,
                                                float* __restrict__ out) {
    int slice = blockIdx.x & 7;
    int node  = (blockIdx.x >> 3) * 256 + threadIdx.x;
    if (node >= N_NODES) return;
    float dv  = dinv[node];
    float rdv = (dv > 0.f) ? (1.f / dv) : 0.f;

    const float4* xb = (const float4*)((const char*)x + (size_t)node * 384 + slice * 48);
    float4 x0 = xb[0], x1 = xb[1], x2 = xb[2];
    float g0 = gamma[0];
    float o[12] = {g0 * x0.x, g0 * x0.y, g0 * x0.z, g0 * x0.w,
                   g0 * x1.x, g0 * x1.y, g0 * x1.z, g0 * x1.w,
                   g0 * x2.x, g0 * x2.y, g0 * x2.z, g0 * x2.w};

    const char* p = p_base + SLAB + (size_t)slice * SLICE_STRIDE + (size_t)node * ROWB;
    for (int k = 1; k <= STEPS; ++k) {
        uint4 qa = *(const uint4*)p;
        uint2 qb = *(const uint2*)(p + 16);
        p += SLAB;
        float gk = gamma[k] * rdv;
        const __half2* h = (const __half2*)&qa;
        #pragma unroll
        for (int i = 0; i < 4; ++i) {
            float2 f = __half22float2(h[i]);
            o[2 * i]     = fmaf(gk, f.x, o[2 * i]);
            o[2 * i + 1] = fmaf(gk, f.y, o[2 * i + 1]);
        }
        const __half2* h2 = (const __half2*)&qb;
        #pragma unroll
        for (int i = 0; i < 2; ++i) {
            float2 f = __half22float2(h2[i]);
            o[8 + 2 * i] = fmaf(gk, f.x, o[8 + 2 * i]);
            o[9 + 2 * i] = fmaf(gk, f.y, o[9 + 2 * i]);
        }
    }
    float4* ob = (float4*)((char*)out + (size_t)node * 384 + slice * 48);
    ob[0] = make_float4(o[0], o[1], o[2], o[3]);
    ob[1] = make_float4(o[4], o[5], o[6], o[7]);
    ob[2] = make_float4(o[8], o[9], o[10], o[11]);
}

// ---------- launch ----------

static inline size_t align_up(size_t v, size_t a) { return (v + a - 1) & ~(a - 1); }

extern "C" void kernel_launch(void* const* d_in, const int* in_sizes, int n_in,
                              void* d_out, int out_size, void* d_ws, size_t ws_size,
                              hipStream_t stream) {
    const float* x     = (const float*)d_in[0];
    const int*   ei    = (const int*)d_in[1];
    const float* gamma = (const float*)d_in[2];
    float*       out   = (float*)d_out;

    const int n  = N_NODES;
    const int ne = N_EDGES;
    const int nblk_nodes = (n + 255) / 256;          // 196
    const int ne_pad_max = ne + 4 * n;               // padded CSR capacity (1.0M)

    char*  ws  = (char*)d_ws;
    size_t off = 0;
    int*   deg      = (int*)(ws + off);   off = align_up(off + (size_t)n * 4, 256);
    int*   row_ptr  = (int*)(ws + off);   off = align_up(off + (size_t)(n + 1) * 4, 256);
    int*   partials = (int*)(ws + off);   off = align_up(off + (size_t)nblk_nodes * 4, 256);
    float* dinv     = (float*)(ws + off); off = align_up(off + (size_t)n * 4, 256);
    unsigned short* cs = (unsigned short*)(ws + off);
    off = align_up(off + (size_t)ne_pad_max * 2, 256);
    char*  p_base   = ws + off;

    const bool deferred = (ws_size >= off + 11ull * SLAB);
    const int  nbuf     = deferred ? 11 : 2;

    (void)hipMemsetAsync(deg, 0, (size_t)n * 4, stream);

    const int nblk_e4 = (ne / 4 + 255) / 256;        // 782
    count_deg<<<nblk_e4, 256, 0, stream>>>(ei, deg, ne);

    scan1<<<nblk_nodes, 256, 0, stream>>>(deg, row_ptr, partials, dinv, n);
    scan2<<<1, 256, 0, stream>>>(partials, nblk_nodes);
    scan3<<<nblk_nodes, 256, 0, stream>>>(row_ptr, partials, n);

    pad_fill<<<nblk_nodes, 256, 0, stream>>>(deg, row_ptr, cs, n);
    fill_csr<<<nblk_e4, 256, 0, stream>>>(ei, row_ptr, deg, cs, ne);

    const int nblk_sl = NSLICE * nblk_nodes;          // 1568
    prescale16<<<nblk_sl, 256, 0, stream>>>(x, dinv, p_base);
    zero_sent<<<1, 256, 0, stream>>>(p_base, nbuf);

    if (deferred) {
        for (int k = 0; k < STEPS; ++k) {
            const char* pin  = p_base + (size_t)k * SLAB;
            char*       pout = p_base + (size_t)(k + 1) * SLAB;
            prop16<<<nblk_sl, 256, 0, stream>>>(pin, pout, nullptr, x,
                                                row_ptr, cs, dinv, gamma, k);
        }
        finalize<<<nblk_sl, 256, 0, stream>>>(p_base, x, dinv, gamma, out);
    } else {
        char* pA = p_base;
        char* pB = p_base + SLAB;
        const char* pin = pA;
        char* pout = pB;
        for (int k = 0; k < STEPS; ++k) {
            char* pw = (k == STEPS - 1) ? nullptr : pout;
            prop16<<<nblk_sl, 256, 0, stream>>>(pin, pw, out, x,
                                                row_ptr, cs, dinv, gamma, k);
            pin  = pout;
            pout = (pout == pB) ? pA : pB;
        }
    }
}

// Round 9
// 449.202 us; speedup vs baseline: 1.5733x; 1.5733x over previous
//
#include <hip/hip_runtime.h>
#include <hip/hip_fp16.h>

#define N_NODES 50000
#define N_EDGES 800000
#define CH 96
#define NSLICE 4           // channel slices; slice = blockIdx%4 -> XCD pair {s, s+4}
#define CPN 3              // 16B chunks per (node,slice): 3*16B = 48B = 24 fp16 channels
#define ROWB 64            // row padded to one 64B cache line (48B used)
#define STEPS 10
#define SENT N_NODES       // sentinel src row (kept zero in every slice)
#define NDST_X 6250        // dst nodes per XCD range (50000/8)

#define SLICE_STRIDE 3200256ull         // align256((N_NODES+1)*ROWB)
#define SLAB (4ull * SLICE_STRIDE)      // one p_k, all slices (~12.8MB)

// ---------- CSR build (XCD-local atomics: 8x duplicated, dst-range partitioned) ----------

__global__ void count_deg(const int* __restrict__ ei, int* __restrict__ deg, int ne) {
    int xr = blockIdx.x & 7;                       // dst-range id ~ XCD id
    int lo = xr * NDST_X, hi = lo + NDST_X;
    int t = (blockIdx.x >> 3) * 256 + threadIdx.x;
    int e = t * 4;
    if (e < ne) {
        int4 d4 = *(const int4*)(ei + ne + e);
        if (d4.x >= lo && d4.x < hi) atomicAdd(&deg[d4.x], 1);
        if (d4.y >= lo && d4.y < hi) atomicAdd(&deg[d4.y], 1);
        if (d4.z >= lo && d4.z < hi) atomicAdd(&deg[d4.z], 1);
        if (d4.w >= lo && d4.w < hi) atomicAdd(&deg[d4.w], 1);
    }
}

// scan1 also computes dinv; row_ptr built over PADDED degrees (round up to 4)
__global__ void scan1(const int* __restrict__ deg, int* __restrict__ row_ptr,
                      int* __restrict__ partials, float* __restrict__ dinv, int n) {
    __shared__ int sm[256];
    int i = blockIdx.x * 256 + threadIdx.x;
    int v = 0;
    if (i < n) {
        int d = deg[i];
        dinv[i] = (d > 0) ? (1.0f / sqrtf((float)d)) : 0.0f;
        v = (d + 3) & ~3;
    }
    sm[threadIdx.x] = v;
    __syncthreads();
    for (int off = 1; off < 256; off <<= 1) {
        int t = (threadIdx.x >= off) ? sm[threadIdx.x - off] : 0;
        __syncthreads();
        sm[threadIdx.x] += t;
        __syncthreads();
    }
    if (i < n) row_ptr[i + 1] = sm[threadIdx.x];
    if (threadIdx.x == 255) partials[blockIdx.x] = sm[255];
}

__global__ void scan2(int* __restrict__ partials, int nb) {
    __shared__ int sm[256];
    int v = (threadIdx.x < nb) ? partials[threadIdx.x] : 0;
    sm[threadIdx.x] = v;
    __syncthreads();
    for (int off = 1; off < 256; off <<= 1) {
        int t = (threadIdx.x >= off) ? sm[threadIdx.x - off] : 0;
        __syncthreads();
        sm[threadIdx.x] += t;
        __syncthreads();
    }
    if (threadIdx.x < nb) partials[threadIdx.x] = sm[threadIdx.x] - v;
}

__global__ void scan3(int* __restrict__ row_ptr, const int* __restrict__ partials, int n) {
    int i = blockIdx.x * 256 + threadIdx.x;
    if (i < n) row_ptr[i + 1] += partials[blockIdx.x];
    if (i == 0) row_ptr[0] = 0;
}

__global__ void pad_fill(const int* __restrict__ deg, const int* __restrict__ row_ptr,
                         unsigned short* __restrict__ cs, int n) {
    int i = blockIdx.x * blockDim.x + threadIdx.x;
    if (i < n) {
        int dg = deg[i];
        int dp = (dg + 3) & ~3;
        int base = row_ptr[i];
        for (int j = dg; j < dp; ++j) cs[base + j] = (unsigned short)SENT;
    }
}

// scatter src (u16) into dst-grouped slots; XCD-local (dst-range partitioned);
// deg doubles as cursor via atomicSub.
__global__ void fill_csr(const int* __restrict__ ei, const int* __restrict__ row_ptr,
                         int* __restrict__ deg, unsigned short* __restrict__ cs, int ne) {
    int xr = blockIdx.x & 7;
    int lo = xr * NDST_X, hi = lo + NDST_X;
    int t = (blockIdx.x >> 3) * 256 + threadIdx.x;
    int e = t * 4;
    if (e < ne) {
        int4 s4 = *(const int4*)(ei + e);
        int4 d4 = *(const int4*)(ei + ne + e);
        #pragma unroll
        for (int j = 0; j < 4; ++j) {
            int s = (j == 0) ? s4.x : (j == 1) ? s4.y : (j == 2) ? s4.z : s4.w;
            int d = (j == 0) ? d4.x : (j == 1) ? d4.y : (j == 2) ? d4.z : d4.w;
            if (d < lo || d >= hi) continue;
            if ((unsigned)s >= (unsigned)N_NODES) s = SENT;
            int slot = atomicSub(&deg[d], 1) - 1;
            cs[row_ptr[d] + slot] = (unsigned short)s;
        }
    }
}

// p0[slice][node] chunk = fp16(dinv * x[node][slice*24 + chunk*8 .. +8])
__global__ __launch_bounds__(256) void prescale16(const float* __restrict__ x,
                                                  const float* __restrict__ dinv,
                                                  char* __restrict__ p0) {
    int slice = blockIdx.x & 3;
    int t = (blockIdx.x >> 2) * 256 + threadIdx.x;        // over N_NODES*CPN
    if (t >= N_NODES * CPN) return;
    int node = t / CPN;
    int chunk = t - node * CPN;
    float dv = dinv[node];
    const float4* xb = (const float4*)((const char*)x + (size_t)node * 384 + slice * 96 + chunk * 32);
    float4 x0 = xb[0], x1 = xb[1];
    uint4 q;
    ((__half2*)&q)[0] = __floats2half2_rn(dv * x0.x, dv * x0.y);
    ((__half2*)&q)[1] = __floats2half2_rn(dv * x0.z, dv * x0.w);
    ((__half2*)&q)[2] = __floats2half2_rn(dv * x1.x, dv * x1.y);
    ((__half2*)&q)[3] = __floats2half2_rn(dv * x1.z, dv * x1.w);
    *(uint4*)(p0 + (size_t)slice * SLICE_STRIDE + (size_t)node * ROWB + chunk * 16) = q;
}

// zero the used 48B of the sentinel row in every slice of every slab
__global__ void zero_sent(char* __restrict__ p_base, int nbuf) {
    int t = blockIdx.x * blockDim.x + threadIdx.x;        // nbuf * NSLICE * CPN threads
    if (t < nbuf * NSLICE * CPN) {
        int chunk = t % CPN;
        int slice = (t / CPN) % NSLICE;
        int buf   = t / (CPN * NSLICE);
        uint4 z = {0u, 0u, 0u, 0u};
        *(uint4*)(p_base + (size_t)buf * SLAB + (size_t)slice * SLICE_STRIDE
                  + (size_t)SENT * ROWB + chunk * 16) = z;
    }
}

__device__ inline void acc8(float* a, uint4 q) {
    const __half2* h = (const __half2*)&q;
    #pragma unroll
    for (int i = 0; i < 4; ++i) {
        float2 f = __half22float2(h[i]);
        a[2 * i] += f.x; a[2 * i + 1] += f.y;
    }
}

// ---------- propagation ----------
// slice = blockIdx%4 (XCD pair {s,s+4}); 3.2MB slice slab is L2-resident.
// 3 lanes per (node,slice) read contiguous 48B of a 64B-aligned row -> 1 line/edge/slice.
__global__ __launch_bounds__(256) void prop16(const char* __restrict__ pin_slab,
                                              char* __restrict__ pout_slab,
                                              float* __restrict__ out,
                                              const float* __restrict__ x,
                                              const int* __restrict__ row_ptr,
                                              const unsigned short* __restrict__ cs,
                                              const float* __restrict__ dinv,
                                              const float* __restrict__ gamma, int k) {
    int slice = blockIdx.x & 3;
    int t = (blockIdx.x >> 2) * 256 + threadIdx.x;        // over N_NODES*CPN
    if (t >= N_NODES * CPN) return;
    int node = t / CPN;
    int chunk = t - node * CPN;
    const char* pin = pin_slab + (size_t)slice * SLICE_STRIDE + chunk * 16;
    int beg = row_ptr[node];
    int end = row_ptr[node + 1];                          // multiple of 4

    float acc[8] = {0.f, 0.f, 0.f, 0.f, 0.f, 0.f, 0.f, 0.f};

    for (int e = beg; e < end; e += 4) {
        ushort4 m = *(const ushort4*)(cs + e);
        uint4 q0 = *(const uint4*)(pin + (size_t)m.x * ROWB);
        uint4 q1 = *(const uint4*)(pin + (size_t)m.y * ROWB);
        uint4 q2 = *(const uint4*)(pin + (size_t)m.z * ROWB);
        uint4 q3 = *(const uint4*)(pin + (size_t)m.w * ROWB);
        acc8(acc, q0);
        acc8(acc, q1);
        acc8(acc, q2);
        acc8(acc, q3);
    }

    float dv = dinv[node];

    if (pout_slab) {                        // p_out = fp16(dinv^2 * S)
        float s = dv * dv;
        uint4 q;
        ((__half2*)&q)[0] = __floats2half2_rn(s * acc[0], s * acc[1]);
        ((__half2*)&q)[1] = __floats2half2_rn(s * acc[2], s * acc[3]);
        ((__half2*)&q)[2] = __floats2half2_rn(s * acc[4], s * acc[5]);
        ((__half2*)&q)[3] = __floats2half2_rn(s * acc[6], s * acc[7]);
        *(uint4*)(pout_slab + (size_t)slice * SLICE_STRIDE + (size_t)node * ROWB + chunk * 16) = q;
    }

    if (out) {                              // fallback: per-step out RMW (8 channels)
        float gk = gamma[k + 1] * dv;       // out += gamma*(dinv*S)
        float4* ob = (float4*)((char*)out + (size_t)node * 384 + slice * 96 + chunk * 32);
        float4 o0, o1;
        if (k == 0) {
            float g0 = gamma[0];
            const float4* xb = (const float4*)((const char*)x + (size_t)node * 384 + slice * 96 + chunk * 32);
            float4 x0 = xb[0], x1 = xb[1];
            o0.x = fmaf(gk, acc[0], g0 * x0.x); o0.y = fmaf(gk, acc[1], g0 * x0.y);
            o0.z = fmaf(gk, acc[2], g0 * x0.z); o0.w = fmaf(gk, acc[3], g0 * x0.w);
            o1.x = fmaf(gk, acc[4], g0 * x1.x); o1.y = fmaf(gk, acc[5], g0 * x1.y);
            o1.z = fmaf(gk, acc[6], g0 * x1.z); o1.w = fmaf(gk, acc[7], g0 * x1.w);
        } else {
            o0 = ob[0]; o1 = ob[1];
            o0.x = fmaf(gk, acc[0], o0.x); o0.y = fmaf(gk, acc[1], o0.y);
            o0.z = fmaf(gk, acc[2], o0.z); o0.w = fmaf(gk, acc[3], o0.w);
            o1.x = fmaf(gk, acc[4], o1.x); o1.y = fmaf(gk, acc[5], o1.y);
            o1.z = fmaf(gk, acc[6], o1.z); o1.w = fmaf(gk, acc[7], o1.w);
        }
        ob[0] = o0; ob[1] = o1;
    }
}

// deferred: out = gamma0*x + sum_k gamma_k * (p_k / dinv)
__global__ __launch_bounds__(256) void finalize(const char* __restrict__ p_base,
                                                const float* __restrict__ x,
                                                const float* __restrict__ dinv,
                                                const float* __restrict__ gamma,
                                                float* __restrict__ out) {
    int slice = blockIdx.x & 3;
    int t = (blockIdx.x >> 2) * 256 + threadIdx.x;
    if (t >= N_NODES * CPN) return;
    int node = t / CPN;
    int chunk = t - node * CPN;
    float dv  = dinv[node];
    float rdv = (dv > 0.f) ? (1.f / dv) : 0.f;

    const float4* xb = (const float4*)((const char*)x + (size_t)node * 384 + slice * 96 + chunk * 32);
    float4 x0 = xb[0], x1 = xb[1];
    float g0 = gamma[0];
    float o[8] = {g0 * x0.x, g0 * x0.y, g0 * x0.z, g0 * x0.w,
                  g0 * x1.x, g0 * x1.y, g0 * x1.z, g0 * x1.w};

    const char* p = p_base + SLAB + (size_t)slice * SLICE_STRIDE + (size_t)node * ROWB + chunk * 16;
    for (int k = 1; k <= STEPS; ++k) {
        uint4 q = *(const uint4*)p;
        p += SLAB;
        float gk = gamma[k] * rdv;
        const __half2* h = (const __half2*)&q;
        #pragma unroll
        for (int i = 0; i < 4; ++i) {
            float2 f = __half22float2(h[i]);
            o[2 * i]     = fmaf(gk, f.x, o[2 * i]);
            o[2 * i + 1] = fmaf(gk, f.y, o[2 * i + 1]);
        }
    }
    float4* ob = (float4*)((char*)out + (size_t)node * 384 + slice * 96 + chunk * 32);
    ob[0] = make_float4(o[0], o[1], o[2], o[3]);
    ob[1] = make_float4(o[4], o[5], o[6], o[7]);
}

// ---------- launch ----------

static inline size_t align_up(size_t v, size_t a) { return (v + a - 1) & ~(a - 1); }

extern "C" void kernel_launch(void* const* d_in, const int* in_sizes, int n_in,
                              void* d_out, int out_size, void* d_ws, size_t ws_size,
                              hipStream_t stream) {
    const float* x     = (const float*)d_in[0];
    const int*   ei    = (const int*)d_in[1];
    const float* gamma = (const float*)d_in[2];
    float*       out   = (float*)d_out;

    const int n  = N_NODES;
    const int ne = N_EDGES;
    const int nblk_nodes = (n + 255) / 256;          // 196
    const int ne_pad_max = ne + 4 * n;               // padded CSR capacity (1.0M)

    char*  ws  = (char*)d_ws;
    size_t off = 0;
    int*   deg      = (int*)(ws + off);   off = align_up(off + (size_t)n * 4, 256);
    int*   row_ptr  = (int*)(ws + off);   off = align_up(off + (size_t)(n + 1) * 4, 256);
    int*   partials = (int*)(ws + off);   off = align_up(off + (size_t)nblk_nodes * 4, 256);
    float* dinv     = (float*)(ws + off); off = align_up(off + (size_t)n * 4, 256);
    unsigned short* cs = (unsigned short*)(ws + off);
    off = align_up(off + (size_t)ne_pad_max * 2, 256);
    char*  p_base   = ws + off;

    const bool deferred = (ws_size >= off + 11ull * SLAB);
    const int  nbuf     = deferred ? 11 : 2;

    (void)hipMemsetAsync(deg, 0, (size_t)n * 4, stream);

    const int nblk_e4 = (ne / 4 + 255) / 256;        // 782 edge-chunk blocks
    count_deg<<<8 * nblk_e4, 256, 0, stream>>>(ei, deg, ne);

    scan1<<<nblk_nodes, 256, 0, stream>>>(deg, row_ptr, partials, dinv, n);
    scan2<<<1, 256, 0, stream>>>(partials, nblk_nodes);
    scan3<<<nblk_nodes, 256, 0, stream>>>(row_ptr, partials, n);

    pad_fill<<<nblk_nodes, 256, 0, stream>>>(deg, row_ptr, cs, n);
    fill_csr<<<8 * nblk_e4, 256, 0, stream>>>(ei, row_ptr, deg, cs, ne);

    const int nt = n * CPN;                           // 150K threads per slice
    const int nblk_t = (nt + 255) / 256;              // 586
    const int nblk_sl = NSLICE * nblk_t;              // 2344
    prescale16<<<nblk_sl, 256, 0, stream>>>(x, dinv, p_base);
    zero_sent<<<1, 256, 0, stream>>>(p_base, nbuf);

    if (deferred) {
        for (int k = 0; k < STEPS; ++k) {
            const char* pin  = p_base + (size_t)k * SLAB;
            char*       pout = p_base + (size_t)(k + 1) * SLAB;
            prop16<<<nblk_sl, 256, 0, stream>>>(pin, pout, nullptr, x,
                                                row_ptr, cs, dinv, gamma, k);
        }
        finalize<<<nblk_sl, 256, 0, stream>>>(p_base, x, dinv, gamma, out);
    } else {
        char* pA = p_base;
        char* pB = p_base + SLAB;
        const char* pin = pA;
        char* pout = pB;
        for (int k = 0; k < STEPS; ++k) {
            char* pw = (k == STEPS - 1) ? nullptr : pout;
            prop16<<<nblk_sl, 256, 0, stream>>>(pin, pw, out, x,
                                                row_ptr, cs, dinv, gamma, k);
            pin  = pout;
            pout = (pout == pB) ? pA : pB;
        }
    }
}

// Round 10
// 415.101 us; speedup vs baseline: 1.7026x; 1.0822x over previous
//
#include <hip/hip_runtime.h>
#include <hip/hip_fp16.h>

#define N_NODES 50000
#define N_EDGES 800000
#define CH 96
#define NSLICE 3            // channel slices of 32ch: one 64B line per (edge,slice)
#define SUBS 4              // 16B sub-chunks per 64B row
#define ROWB 64             // fully-packed row: 32ch * 2B = 64B, zero pad
#define STEPS 10
#define SENT N_NODES        // sentinel src row (kept zero in every slice)
#define NDST_X 6250         // dst nodes per XCD range (50000/8) for setup dup
#define LANES_PER_SLICE (N_NODES * SUBS)          // 200000
#define NBLK_SLICE 782                            // ceil(200000/256)
#define PROP_ROUNDS 391                           // slice2 (2 XCDs) needs 391*2=782
#define PROP_GRID (PROP_ROUNDS * 8)               // 3128 blocks

#define SLICE3 3200256ull                         // align256((N_NODES+1)*ROWB)
#define SLAB (3ull * SLICE3)                      // one p_k, ~9.6MB

// ---------- CSR build (XCD-local atomics: 8x duplicated, dst-range partitioned) ----------

__global__ void count_deg(const int* __restrict__ ei, int* __restrict__ deg, int ne) {
    int xr = blockIdx.x & 7;
    int lo = xr * NDST_X, hi = lo + NDST_X;
    int t = (blockIdx.x >> 3) * 256 + threadIdx.x;
    int e = t * 4;
    if (e < ne) {
        int4 d4 = *(const int4*)(ei + ne + e);
        if (d4.x >= lo && d4.x < hi) atomicAdd(&deg[d4.x], 1);
        if (d4.y >= lo && d4.y < hi) atomicAdd(&deg[d4.y], 1);
        if (d4.z >= lo && d4.z < hi) atomicAdd(&deg[d4.z], 1);
        if (d4.w >= lo && d4.w < hi) atomicAdd(&deg[d4.w], 1);
    }
}

__global__ void scan1(const int* __restrict__ deg, int* __restrict__ row_ptr,
                      int* __restrict__ partials, float* __restrict__ dinv, int n) {
    __shared__ int sm[256];
    int i = blockIdx.x * 256 + threadIdx.x;
    int v = 0;
    if (i < n) {
        int d = deg[i];
        dinv[i] = (d > 0) ? (1.0f / sqrtf((float)d)) : 0.0f;
        v = (d + 3) & ~3;
    }
    sm[threadIdx.x] = v;
    __syncthreads();
    for (int off = 1; off < 256; off <<= 1) {
        int t = (threadIdx.x >= off) ? sm[threadIdx.x - off] : 0;
        __syncthreads();
        sm[threadIdx.x] += t;
        __syncthreads();
    }
    if (i < n) row_ptr[i + 1] = sm[threadIdx.x];
    if (threadIdx.x == 255) partials[blockIdx.x] = sm[255];
}

__global__ void scan2(int* __restrict__ partials, int nb) {
    __shared__ int sm[256];
    int v = (threadIdx.x < nb) ? partials[threadIdx.x] : 0;
    sm[threadIdx.x] = v;
    __syncthreads();
    for (int off = 1; off < 256; off <<= 1) {
        int t = (threadIdx.x >= off) ? sm[threadIdx.x - off] : 0;
        __syncthreads();
        sm[threadIdx.x] += t;
        __syncthreads();
    }
    if (threadIdx.x < nb) partials[threadIdx.x] = sm[threadIdx.x] - v;
}

__global__ void scan3(int* __restrict__ row_ptr, const int* __restrict__ partials, int n) {
    int i = blockIdx.x * 256 + threadIdx.x;
    if (i < n) row_ptr[i + 1] += partials[blockIdx.x];
    if (i == 0) row_ptr[0] = 0;
}

__global__ void pad_fill(const int* __restrict__ deg, const int* __restrict__ row_ptr,
                         unsigned short* __restrict__ cs, int n) {
    int i = blockIdx.x * blockDim.x + threadIdx.x;
    if (i < n) {
        int dg = deg[i];
        int dp = (dg + 3) & ~3;
        int base = row_ptr[i];
        for (int j = dg; j < dp; ++j) cs[base + j] = (unsigned short)SENT;
    }
}

__global__ void fill_csr(const int* __restrict__ ei, const int* __restrict__ row_ptr,
                         int* __restrict__ deg, unsigned short* __restrict__ cs, int ne) {
    int xr = blockIdx.x & 7;
    int lo = xr * NDST_X, hi = lo + NDST_X;
    int t = (blockIdx.x >> 3) * 256 + threadIdx.x;
    int e = t * 4;
    if (e < ne) {
        int4 s4 = *(const int4*)(ei + e);
        int4 d4 = *(const int4*)(ei + ne + e);
        #pragma unroll
        for (int j = 0; j < 4; ++j) {
            int s = (j == 0) ? s4.x : (j == 1) ? s4.y : (j == 2) ? s4.z : s4.w;
            int d = (j == 0) ? d4.x : (j == 1) ? d4.y : (j == 2) ? d4.z : d4.w;
            if (d < lo || d >= hi) continue;
            if ((unsigned)s >= (unsigned)N_NODES) s = SENT;
            int slot = atomicSub(&deg[d], 1) - 1;
            cs[row_ptr[d] + slot] = (unsigned short)s;
        }
    }
}

// p0[slice][node][sub] = fp16(dinv * x[node][slice*32 + sub*8 .. +8])
__global__ __launch_bounds__(256) void prescale16(const float* __restrict__ x,
                                                  const float* __restrict__ dinv,
                                                  char* __restrict__ p0) {
    int idx = blockIdx.x * 256 + threadIdx.x;
    if (idx >= NSLICE * LANES_PER_SLICE) return;
    int slice = idx / LANES_PER_SLICE;
    int rem   = idx - slice * LANES_PER_SLICE;
    int node  = rem >> 2;
    int sub   = rem & 3;
    float dv = dinv[node];
    const float4* xb = (const float4*)((const char*)x + (size_t)node * 384 + slice * 128 + sub * 32);
    float4 x0 = xb[0], x1 = xb[1];
    uint4 q;
    ((__half2*)&q)[0] = __floats2half2_rn(dv * x0.x, dv * x0.y);
    ((__half2*)&q)[1] = __floats2half2_rn(dv * x0.z, dv * x0.w);
    ((__half2*)&q)[2] = __floats2half2_rn(dv * x1.x, dv * x1.y);
    ((__half2*)&q)[3] = __floats2half2_rn(dv * x1.z, dv * x1.w);
    *(uint4*)(p0 + (size_t)slice * SLICE3 + (size_t)node * ROWB + sub * 16) = q;
}

__global__ void zero_sent(char* __restrict__ p_base, int nbuf) {
    int t = blockIdx.x * 256 + threadIdx.x;
    if (t < nbuf * NSLICE * SUBS) {
        int sub   = t & 3;
        int slice = (t >> 2) % NSLICE;
        int buf   = t / (SUBS * NSLICE);
        uint4 z = {0u, 0u, 0u, 0u};
        *(uint4*)(p_base + (size_t)buf * SLAB + (size_t)slice * SLICE3
                  + (size_t)SENT * ROWB + sub * 16) = z;
    }
}

__device__ inline void acc8(float* a, uint4 q) {
    const __half2* h = (const __half2*)&q;
    #pragma unroll
    for (int i = 0; i < 4; ++i) {
        float2 f = __half22float2(h[i]);
        a[2 * i] += f.x; a[2 * i + 1] += f.y;
    }
}

// ---------- propagation ----------
// XCD groups {0,1,2}->slice0, {3,4,5}->slice1, {6,7}->slice2 (slice slab 3.2MB,
// L2-resident per XCD). 4 lanes per (node,slice) read one fully-packed 64B row
// -> exactly 1 cache line per (edge,slice), 3 lines/edge total.
__global__ __launch_bounds__(256) void prop16(const char* __restrict__ pin_slab,
                                              char* __restrict__ pout_slab,
                                              float* __restrict__ out,
                                              const float* __restrict__ x,
                                              const int* __restrict__ row_ptr,
                                              const unsigned short* __restrict__ cs,
                                              const float* __restrict__ dinv,
                                              const float* __restrict__ gamma, int k) {
    int xcd = blockIdx.x & 7;
    int r   = blockIdx.x >> 3;
    int slice, pos, gsz;
    if (xcd < 3)      { slice = 0; pos = xcd;     gsz = 3; }
    else if (xcd < 6) { slice = 1; pos = xcd - 3; gsz = 3; }
    else              { slice = 2; pos = xcd - 6; gsz = 2; }
    int lb = r * gsz + pos;
    if (lb >= NBLK_SLICE) return;
    int t = lb * 256 + threadIdx.x;
    if (t >= LANES_PER_SLICE) return;
    int node = t >> 2;
    int sub  = t & 3;

    const char* pin = pin_slab + (size_t)slice * SLICE3 + sub * 16;
    int beg = row_ptr[node];
    int end = row_ptr[node + 1];                  // multiple of 4

    float acc[8] = {0.f, 0.f, 0.f, 0.f, 0.f, 0.f, 0.f, 0.f};

    for (int e = beg; e < end; e += 4) {
        ushort4 m = *(const ushort4*)(cs + e);    // broadcast across the 4 lanes
        uint4 q0 = *(const uint4*)(pin + (size_t)m.x * ROWB);
        uint4 q1 = *(const uint4*)(pin + (size_t)m.y * ROWB);
        uint4 q2 = *(const uint4*)(pin + (size_t)m.z * ROWB);
        uint4 q3 = *(const uint4*)(pin + (size_t)m.w * ROWB);
        acc8(acc, q0);
        acc8(acc, q1);
        acc8(acc, q2);
        acc8(acc, q3);
    }

    float dv = dinv[node];

    if (pout_slab) {                              // p_out = fp16(dinv^2 * S)
        float s = dv * dv;
        uint4 q;
        ((__half2*)&q)[0] = __floats2half2_rn(s * acc[0], s * acc[1]);
        ((__half2*)&q)[1] = __floats2half2_rn(s * acc[2], s * acc[3]);
        ((__half2*)&q)[2] = __floats2half2_rn(s * acc[4], s * acc[5]);
        ((__half2*)&q)[3] = __floats2half2_rn(s * acc[6], s * acc[7]);
        *(uint4*)(pout_slab + (size_t)slice * SLICE3 + (size_t)node * ROWB + sub * 16) = q;
    }

    if (out) {                                    // fallback: per-step out RMW (8 ch)
        float gk = gamma[k + 1] * dv;
        float4* ob = (float4*)((char*)out + (size_t)node * 384 + slice * 128 + sub * 32);
        float4 o0, o1;
        if (k == 0) {
            float g0 = gamma[0];
            const float4* xb = (const float4*)((const char*)x + (size_t)node * 384 + slice * 128 + sub * 32);
            float4 x0 = xb[0], x1 = xb[1];
            o0.x = fmaf(gk, acc[0], g0 * x0.x); o0.y = fmaf(gk, acc[1], g0 * x0.y);
            o0.z = fmaf(gk, acc[2], g0 * x0.z); o0.w = fmaf(gk, acc[3], g0 * x0.w);
            o1.x = fmaf(gk, acc[4], g0 * x1.x); o1.y = fmaf(gk, acc[5], g0 * x1.y);
            o1.z = fmaf(gk, acc[6], g0 * x1.z); o1.w = fmaf(gk, acc[7], g0 * x1.w);
        } else {
            o0 = ob[0]; o1 = ob[1];
            o0.x = fmaf(gk, acc[0], o0.x); o0.y = fmaf(gk, acc[1], o0.y);
            o0.z = fmaf(gk, acc[2], o0.z); o0.w = fmaf(gk, acc[3], o0.w);
            o1.x = fmaf(gk, acc[4], o1.x); o1.y = fmaf(gk, acc[5], o1.y);
            o1.z = fmaf(gk, acc[6], o1.z); o1.w = fmaf(gk, acc[7], o1.w);
        }
        ob[0] = o0; ob[1] = o1;
    }
}

// deferred: out = gamma0*x + sum_k gamma_k * (p_k / dinv)
__global__ __launch_bounds__(256) void finalize(const char* __restrict__ p_base,
                                                const float* __restrict__ x,
                                                const float* __restrict__ dinv,
                                                const float* __restrict__ gamma,
                                                float* __restrict__ out) {
    int idx = blockIdx.x * 256 + threadIdx.x;
    if (idx >= NSLICE * LANES_PER_SLICE) return;
    int slice = idx / LANES_PER_SLICE;
    int rem   = idx - slice * LANES_PER_SLICE;
    int node  = rem >> 2;
    int sub   = rem & 3;
    float dv  = dinv[node];
    float rdv = (dv > 0.f) ? (1.f / dv) : 0.f;

    const float4* xb = (const float4*)((const char*)x + (size_t)node * 384 + slice * 128 + sub * 32);
    float4 x0 = xb[0], x1 = xb[1];
    float g0 = gamma[0];
    float o[8] = {g0 * x0.x, g0 * x0.y, g0 * x0.z, g0 * x0.w,
                  g0 * x1.x, g0 * x1.y, g0 * x1.z, g0 * x1.w};

    const char* p = p_base + SLAB + (size_t)slice * SLICE3 + (size_t)node * ROWB + sub * 16;
    for (int k = 1; k <= STEPS; ++k) {
        uint4 q = *(const uint4*)p;
        p += SLAB;
        float gk = gamma[k] * rdv;
        const __half2* h = (const __half2*)&q;
        #pragma unroll
        for (int i = 0; i < 4; ++i) {
            float2 f = __half22float2(h[i]);
            o[2 * i]     = fmaf(gk, f.x, o[2 * i]);
            o[2 * i + 1] = fmaf(gk, f.y, o[2 * i + 1]);
        }
    }
    float4* ob = (float4*)((char*)out + (size_t)node * 384 + slice * 128 + sub * 32);
    ob[0] = make_float4(o[0], o[1], o[2], o[3]);
    ob[1] = make_float4(o[4], o[5], o[6], o[7]);
}

// ---------- launch ----------

static inline size_t align_up(size_t v, size_t a) { return (v + a - 1) & ~(a - 1); }

extern "C" void kernel_launch(void* const* d_in, const int* in_sizes, int n_in,
                              void* d_out, int out_size, void* d_ws, size_t ws_size,
                              hipStream_t stream) {
    const float* x     = (const float*)d_in[0];
    const int*   ei    = (const int*)d_in[1];
    const float* gamma = (const float*)d_in[2];
    float*       out   = (float*)d_out;

    const int n  = N_NODES;
    const int ne = N_EDGES;
    const int nblk_nodes = (n + 255) / 256;          // 196
    const int ne_pad_max = ne + 4 * n;               // padded CSR capacity (1.0M)

    char*  ws  = (char*)d_ws;
    size_t off = 0;
    int*   deg      = (int*)(ws + off);   off = align_up(off + (size_t)n * 4, 256);
    int*   row_ptr  = (int*)(ws + off);   off = align_up(off + (size_t)(n + 1) * 4, 256);
    int*   partials = (int*)(ws + off);   off = align_up(off + (size_t)nblk_nodes * 4, 256);
    float* dinv     = (float*)(ws + off); off = align_up(off + (size_t)n * 4, 256);
    unsigned short* cs = (unsigned short*)(ws + off);
    off = align_up(off + (size_t)ne_pad_max * 2, 256);
    char*  p_base   = ws + off;

    const bool deferred = (ws_size >= off + 11ull * SLAB);   // ~105.6MB needed
    const int  nbuf     = deferred ? 11 : 2;

    (void)hipMemsetAsync(deg, 0, (size_t)n * 4, stream);

    const int nblk_e4 = (ne / 4 + 255) / 256;        // 782 edge-chunk blocks
    count_deg<<<8 * nblk_e4, 256, 0, stream>>>(ei, deg, ne);

    scan1<<<nblk_nodes, 256, 0, stream>>>(deg, row_ptr, partials, dinv, n);
    scan2<<<1, 256, 0, stream>>>(partials, nblk_nodes);
    scan3<<<nblk_nodes, 256, 0, stream>>>(row_ptr, partials, n);

    pad_fill<<<nblk_nodes, 256, 0, stream>>>(deg, row_ptr, cs, n);
    fill_csr<<<8 * nblk_e4, 256, 0, stream>>>(ei, row_ptr, deg, cs, ne);

    const int nlin = NSLICE * LANES_PER_SLICE;        // 600K lanes
    const int nblk_lin = (nlin + 255) / 256;          // 2344
    prescale16<<<nblk_lin, 256, 0, stream>>>(x, dinv, p_base);
    zero_sent<<<1, 256, 0, stream>>>(p_base, nbuf);

    if (deferred) {
        for (int k = 0; k < STEPS; ++k) {
            const char* pin  = p_base + (size_t)k * SLAB;
            char*       pout = p_base + (size_t)(k + 1) * SLAB;
            prop16<<<PROP_GRID, 256, 0, stream>>>(pin, pout, nullptr, x,
                                                  row_ptr, cs, dinv, gamma, k);
        }
        finalize<<<nblk_lin, 256, 0, stream>>>(p_base, x, dinv, gamma, out);
    } else {
        char* pA = p_base;
        char* pB = p_base + SLAB;
        const char* pin = pA;
        char* pout = pB;
        for (int k = 0; k < STEPS; ++k) {
            char* pw = (k == STEPS - 1) ? nullptr : pout;
            prop16<<<PROP_GRID, 256, 0, stream>>>(pin, pw, out, x,
                                                  row_ptr, cs, dinv, gamma, k);
            pin  = pout;
            pout = (pout == pB) ? pA : pB;
        }
    }
}